// Round 7
// baseline (4964.063 us; speedup 1.0000x reference)
//
#include <hip/hip_runtime.h>
#include <hip/hip_fp16.h>

#define CN0 200000
#define CN1 100000
#define CN2 50000
#define CM 16
#define CVL 32
#define CK 32
#define CD 64
#define CEPS 1e-12f

// PROFILING: rep-loops keep all three kernels above the ~245us harness fills
// so they land in rocprof top-5 with clean (spill-free) counters.
#define REP_LV0 4
#define REP_C1 5
#define REP_C2 10

typedef _Float16 half2_t __attribute__((ext_vector_type(2)));

__device__ __forceinline__ float lane_bcast(float v, int l) {
    return __int_as_float(__builtin_amdgcn_readlane(__float_as_int(v), l));
}

union H2U { __half2 h2; uint u; };
union H4 { __half2 h2[2]; uint2 u; };

// Stage 0: ft_lv0[n] = concat(sum_m x, 0.5*(s^2 - sum x^2)), fp16 out.
__global__ void k_lv0(const float* __restrict__ x, __half* __restrict__ ft0) {
    int t = blockIdx.x * blockDim.x + threadIdx.x;
    int n = t >> 3;
    int q = t & 7;
    if (n >= CN0) return;
    for (int rep = 0; rep < REP_LV0; ++rep) {
        asm volatile("" ::: "memory");
        const float4* xp = reinterpret_cast<const float4*>(x + (size_t)n * (CM * CVL)) + q;
        float4 s = make_float4(0.f, 0.f, 0.f, 0.f);
        float4 sq = make_float4(0.f, 0.f, 0.f, 0.f);
#pragma unroll
        for (int m = 0; m < CM; ++m) {
            float4 v = xp[m * (CVL / 4)];
            s.x += v.x; s.y += v.y; s.z += v.z; s.w += v.w;
            sq.x += v.x * v.x; sq.y += v.y * v.y; sq.z += v.z * v.z; sq.w += v.w * v.w;
        }
        float4 cr;
        cr.x = 0.5f * (s.x * s.x - sq.x);
        cr.y = 0.5f * (s.y * s.y - sq.y);
        cr.z = 0.5f * (s.z * s.z - sq.z);
        cr.w = 0.5f * (s.w * s.w - sq.w);
        uint2* orow = reinterpret_cast<uint2*>(ft0 + (size_t)n * CD);
        H4 pa, pb;
        pa.h2[0] = __floats2half2_rn(s.x, s.y);
        pa.h2[1] = __floats2half2_rn(s.z, s.w);
        pb.h2[0] = __floats2half2_rn(cr.x, cr.y);
        pb.h2[1] = __floats2half2_rn(cr.z, cr.w);
        orow[q] = pa.u;
        orow[8 + q] = pb.u;
    }
}

// Gather payload: 8 neighbor uint2 (rows 4t+g, dims 4h..4h+3) + self uint2.
__device__ __forceinline__ void load_pay(const __half* __restrict__ ftin,
                                         const int* __restrict__ ids,
                                         const int* __restrict__ adj,
                                         int n, int nNodes, int g, int h,
                                         uint2* nb, uint2& self) {
    const int nc = n < nNodes ? n : nNodes - 1;   // clamp (result unused if OOB)
    const int id = ids[nc];                        // uniform -> s_load
    self = *reinterpret_cast<const uint2*>(ftin + ((size_t)id << 6) + (h << 2));
    const int* arow = adj + (size_t)nc * CK;
    int r[8];
#pragma unroll
    for (int t = 0; t < 8; ++t) r[t] = arow[4 * t + g];   // per-lane dword, 16B span
#pragma unroll
    for (int t = 0; t < 8; ++t)
        nb[t] = *reinterpret_cast<const uint2*>(ftin + ((size_t)r[t] << 6) + (h << 2));
}

__device__ __forceinline__ void consume_pay(const uint2* nb, uint2 self,
                                            float* c0q, float* c1q) {
    float pool[4] = {0.f, 0.f, 0.f, 0.f};
#pragma unroll
    for (int t = 0; t < 8; ++t) {
        half2_t lo = __builtin_bit_cast(half2_t, nb[t].x);
        half2_t hi = __builtin_bit_cast(half2_t, nb[t].y);
        pool[0] += (float)lo.x; pool[1] += (float)lo.y;
        pool[2] += (float)hi.x; pool[3] += (float)hi.y;
    }
#pragma unroll
    for (int d = 0; d < 4; ++d) {
        pool[d] += __shfl_xor(pool[d], 16);   // combine 4 row-groups
        pool[d] += __shfl_xor(pool[d], 32);
    }
    half2_t slo = __builtin_bit_cast(half2_t, self.x);
    half2_t shi = __builtin_bit_cast(half2_t, self.y);
    const float s4[4] = {(float)slo.x, (float)slo.y, (float)shi.x, (float)shi.y};
#pragma unroll
    for (int d = 0; d < 4; ++d) {
        c0q[d] = s4[d] + pool[d];   // conv rows 4h+d
        c1q[d] = s4[d] * pool[d];   // conv rows 64+4h+d
    }
}

// Conv: wave owns P=4 nodes, depth-2 pipelined gather (payload for node p+1
// in flight while consuming node p). lane -> g=lane>>4 (row-group), h=lane&15
// (dim-quad). Matmul f32 vs fp16 W in LDS, readlane-broadcast; lane j = out j.
// c stays f32 (fp16 c overflows at level 2).
template<bool NORM, typename OutT, int REPS>
__launch_bounds__(256, 4)
__global__ void k_conv(const __half* __restrict__ ftin,
                       const int* __restrict__ ids,
                       const int* __restrict__ adj,
                       const float* __restrict__ W,
                       const float* __restrict__ bias,
                       OutT* __restrict__ ftout,
                       int nNodes) {
    __shared__ __half Wt[CD][CD];  // W[i][j]    ("+" half)  8 KiB
    __shared__ __half Wb[CD][CD];  // W[64+i][j] ("*" half)  8 KiB
    __shared__ float bl[CD];
    for (int idx = threadIdx.x; idx < CD * CD / 2; idx += blockDim.x) {
        const int i = idx >> 5;
        const int jp = (idx & 31) << 1;
        H2U t, b;
        t.h2 = __floats2half2_rn(W[i * CD + jp], W[i * CD + jp + 1]);
        b.h2 = __floats2half2_rn(W[(CD + i) * CD + jp], W[(CD + i) * CD + jp + 1]);
        *reinterpret_cast<uint*>(&Wt[i][jp]) = t.u;
        *reinterpret_cast<uint*>(&Wb[i][jp]) = b.u;
    }
    if (threadIdx.x < CD) bl[threadIdx.x] = bias[threadIdx.x];
    __syncthreads();

    const int lane = threadIdx.x & 63;
    const int wave = __builtin_amdgcn_readfirstlane(threadIdx.x >> 6);
    const int g = lane >> 4;
    const int h = lane & 15;
    constexpr int P = 4;
    const int batchNodes = 4 * P;  // 16 nodes per 256-thread block pass
    const int nBatches = (nNodes + batchNodes - 1) / batchNodes;

    for (int rep = 0; rep < REPS; ++rep) {
        asm volatile("" ::: "memory");
        for (int batch = blockIdx.x; batch < nBatches; batch += gridDim.x) {
            const int base =
                __builtin_amdgcn_readfirstlane(batch * batchNodes + wave * P);
            float c0q[P][4], c1q[P][4], acc[P];
            uint2 nbA[8], nbB[8], selfA, selfB;
            // depth-2 pipeline over the 4 nodes
            load_pay(ftin, ids, adj, base + 0, nNodes, g, h, nbA, selfA);
            load_pay(ftin, ids, adj, base + 1, nNodes, g, h, nbB, selfB);
            consume_pay(nbA, selfA, c0q[0], c1q[0]);
            load_pay(ftin, ids, adj, base + 2, nNodes, g, h, nbA, selfA);
            consume_pay(nbB, selfB, c0q[1], c1q[1]);
            load_pay(ftin, ids, adj, base + 3, nNodes, g, h, nbB, selfB);
            consume_pay(nbA, selfA, c0q[2], c1q[2]);
            consume_pay(nbB, selfB, c0q[3], c1q[3]);
#pragma unroll
            for (int p = 0; p < P; ++p) acc[p] = bl[lane];
            // out[j] = b[j] + sum_i c[i]*W[i][j]; c[4hh+d] lives in lane hh reg d.
#pragma unroll
            for (int hh = 0; hh < 16; ++hh) {
#pragma unroll
                for (int d = 0; d < 4; ++d) {
                    const int i = 4 * hh + d;
                    const float wt = __half2float(Wt[i][lane]);
                    const float wb = __half2float(Wb[i][lane]);
#pragma unroll
                    for (int p = 0; p < P; ++p) {
                        acc[p] = fmaf(lane_bcast(c0q[p][d], hh), wt, acc[p]);
                        acc[p] = fmaf(lane_bcast(c1q[p][d], hh), wb, acc[p]);
                    }
                }
            }
            // Epilogue
#pragma unroll
            for (int p = 0; p < P; ++p) {
                const int n = base + p;
                if (n >= nNodes) continue;
                float z = fmaxf(acc[p], 0.f);
                if (NORM) {
                    float ss = z * z;
#pragma unroll
                    for (int off = 32; off >= 1; off >>= 1) ss += __shfl_xor(ss, off);
                    float nrm = fmaxf(sqrtf(ss), CEPS);
                    ftout[(size_t)n * CD + lane] = (OutT)(z / nrm);
                } else {
                    ftout[(size_t)n * CD + lane] = (OutT)z;
                }
            }
        }
    }
}

extern "C" void kernel_launch(void* const* d_in, const int* in_sizes, int n_in,
                              void* d_out, int out_size, void* d_ws, size_t ws_size,
                              hipStream_t stream) {
    const float* node_feats  = (const float*)d_in[0];
    const int*   node_l1_ids = (const int*)d_in[1];
    const int*   adj1        = (const int*)d_in[2];
    const int*   node2_pos   = (const int*)d_in[3];
    const int*   adj2        = (const int*)d_in[4];
    const float* W1          = (const float*)d_in[5];
    const float* b1          = (const float*)d_in[6];
    const float* W2          = (const float*)d_in[7];
    const float* b2          = (const float*)d_in[8];
    float* out = (float*)d_out;

    __half* ft0 = (__half*)d_ws;                  // CN0*CD fp16 = 25.6 MB
    __half* ft1 = ft0 + (size_t)CN0 * CD;         // CN1*CD fp16 = 12.8 MB

    int t1 = CN0 * 8;
    k_lv0<<<(t1 + 255) / 256, 256, 0, stream>>>(node_feats, ft0);
    k_conv<false, __half, REP_C1><<<2048, 256, 0, stream>>>(ft0, node_l1_ids, adj1, W1, b1, ft1, CN1);
    k_conv<true, float, REP_C2><<<2048, 256, 0, stream>>>(ft1, node2_pos, adj2, W2, b2, out, CN2);
}

// Round 8
// 1161.773 us; speedup vs baseline: 4.2728x; 4.2728x over previous
//
#include <hip/hip_runtime.h>
#include <hip/hip_fp16.h>

#define CN0 200000
#define CN1 100000
#define CN2 50000
#define CM 16
#define CVL 32
#define CK 32
#define CD 64
#define CEPS 1e-12f

// PROFILING ROUND: rep-loops wrapped around the UNMODIFIED round-6 kernel
// bodies (the known-good, spill-free, fastest structure) so all three
// kernels exceed the ~245us harness fills and surface in rocprof top-5.
// Only new live state: the rep counter. Production timing this round is
// sacrificial; the read is per-dispatch FETCH/WRITE/VALUBusy.
#define REP_LV0 4
#define REP_C1 5
#define REP_C2 10

__device__ __forceinline__ float lane_bcast(float v, int l) {
    return __int_as_float(__builtin_amdgcn_readlane(__float_as_int(v), l));
}

union H2U { __half2 h2; uint u; };
union H4 { __half2 h2[2]; uint2 u; };

// Stage 0: ft_lv0[n] = concat(sum_m x, 0.5*(s^2 - sum x^2)), fp16 out.
__global__ void k_lv0(const float* __restrict__ x, __half* __restrict__ ft0) {
    int t = blockIdx.x * blockDim.x + threadIdx.x;
    int n = t >> 3;
    int q = t & 7;
    if (n >= CN0) return;
    for (int rep = 0; rep < REP_LV0; ++rep) {
        asm volatile("" ::: "memory");
        const float4* xp = reinterpret_cast<const float4*>(x + (size_t)n * (CM * CVL)) + q;
        float4 s = make_float4(0.f, 0.f, 0.f, 0.f);
        float4 sq = make_float4(0.f, 0.f, 0.f, 0.f);
#pragma unroll
        for (int m = 0; m < CM; ++m) {
            float4 v = xp[m * (CVL / 4)];
            s.x += v.x; s.y += v.y; s.z += v.z; s.w += v.w;
            sq.x += v.x * v.x; sq.y += v.y * v.y; sq.z += v.z * v.z; sq.w += v.w * v.w;
        }
        float4 cr;
        cr.x = 0.5f * (s.x * s.x - sq.x);
        cr.y = 0.5f * (s.y * s.y - sq.y);
        cr.z = 0.5f * (s.z * s.z - sq.z);
        cr.w = 0.5f * (s.w * s.w - sq.w);
        uint2* orow = reinterpret_cast<uint2*>(ft0 + (size_t)n * CD);
        H4 pa, pb;
        pa.h2[0] = __floats2half2_rn(s.x, s.y);
        pa.h2[1] = __floats2half2_rn(s.z, s.w);
        pb.h2[0] = __floats2half2_rn(cr.x, cr.y);
        pb.h2[1] = __floats2half2_rn(cr.z, cr.w);
        orow[q] = pa.u;
        orow[8 + q] = pb.u;
    }
}

// Conv: round-6 structure, UNCHANGED inside the rep loop. One wave owns a
// node's 64-dim row (lane = dim), P=4 nodes per pass, immediate-accumulate
// gather (4 chains), f32 matmul vs fp16 W in LDS, (256,8) occupancy.
template<bool NORM, typename OutT, int REPS>
__launch_bounds__(256, 8)
__global__ void k_conv(const __half* __restrict__ ftin,
                       const int* __restrict__ ids,
                       const int* __restrict__ adj,
                       const float* __restrict__ W,
                       const float* __restrict__ bias,
                       OutT* __restrict__ ftout,
                       int nNodes) {
    __shared__ __half Wt[CD][CD];  // W[i][j]    ("+" half)  8 KiB
    __shared__ __half Wb[CD][CD];  // W[64+i][j] ("*" half)  8 KiB
    __shared__ float bl[CD];
    for (int idx = threadIdx.x; idx < CD * CD / 2; idx += blockDim.x) {
        const int i = idx >> 5;
        const int jp = (idx & 31) << 1;
        H2U t, b;
        t.h2 = __floats2half2_rn(W[i * CD + jp], W[i * CD + jp + 1]);
        b.h2 = __floats2half2_rn(W[(CD + i) * CD + jp], W[(CD + i) * CD + jp + 1]);
        *reinterpret_cast<uint*>(&Wt[i][jp]) = t.u;
        *reinterpret_cast<uint*>(&Wb[i][jp]) = b.u;
    }
    if (threadIdx.x < CD) bl[threadIdx.x] = bias[threadIdx.x];
    __syncthreads();

    const int lane = threadIdx.x & 63;
    const int wave = __builtin_amdgcn_readfirstlane(threadIdx.x >> 6);
    constexpr int P = 4;
    const int batchNodes = 4 * P;  // 16 nodes per 256-thread block pass
    const int nBatches = (nNodes + batchNodes - 1) / batchNodes;

    for (int rep = 0; rep < REPS; ++rep) {
        asm volatile("" ::: "memory");
        for (int batch = blockIdx.x; batch < nBatches; batch += gridDim.x) {
            const int nodeBase =
                __builtin_amdgcn_readfirstlane(batch * batchNodes + wave * P);
            float c0[P], c1[P], acc[P];
#pragma unroll
            for (int p = 0; p < P; ++p) {
                const int n = nodeBase + p;  // wave-uniform
                float n0 = 0.f, pool = 0.f;
                if (n < nNodes) {            // uniform branch
                    const int id = ids[n];   // s_load
                    n0 = __half2float(ftin[((size_t)id << 6) + lane]);
                    const int* arow = adj + (size_t)n * CK;  // uniform -> s_loads
                    float q0 = 0.f, q1 = 0.f, q2 = 0.f, q3 = 0.f;
#pragma unroll 8
                    for (int k = 0; k < CK; k += 4) {
                        q0 += __half2float(ftin[((size_t)arow[k + 0] << 6) + lane]);
                        q1 += __half2float(ftin[((size_t)arow[k + 1] << 6) + lane]);
                        q2 += __half2float(ftin[((size_t)arow[k + 2] << 6) + lane]);
                        q3 += __half2float(ftin[((size_t)arow[k + 3] << 6) + lane]);
                    }
                    pool = (q0 + q1) + (q2 + q3);
                }
                c0[p] = n0 + pool;  // conv row `lane`
                c1[p] = n0 * pool;  // conv row 64+`lane`
                acc[p] = bl[lane];
            }
            // out[j] = b[j] + sum_i c0_i*Wt[i][j] + c1_i*Wb[i][j]; lane = j.
#pragma unroll 8
            for (int i = 0; i < CD; ++i) {
                const float wt = __half2float(Wt[i][lane]);
                const float wb = __half2float(Wb[i][lane]);
#pragma unroll
                for (int p = 0; p < P; ++p) {
                    acc[p] = fmaf(lane_bcast(c0[p], i), wt, acc[p]);
                    acc[p] = fmaf(lane_bcast(c1[p], i), wb, acc[p]);
                }
            }
            // Epilogue
#pragma unroll
            for (int p = 0; p < P; ++p) {
                const int n = nodeBase + p;
                if (n >= nNodes) continue;
                float z = fmaxf(acc[p], 0.f);
                if (NORM) {
                    float ss = z * z;
#pragma unroll
                    for (int off = 32; off >= 1; off >>= 1) ss += __shfl_xor(ss, off);
                    float nrm = fmaxf(sqrtf(ss), CEPS);
                    ftout[(size_t)n * CD + lane] = (OutT)(z / nrm);
                } else {
                    ftout[(size_t)n * CD + lane] = (OutT)z;
                }
            }
        }
    }
}

extern "C" void kernel_launch(void* const* d_in, const int* in_sizes, int n_in,
                              void* d_out, int out_size, void* d_ws, size_t ws_size,
                              hipStream_t stream) {
    const float* node_feats  = (const float*)d_in[0];
    const int*   node_l1_ids = (const int*)d_in[1];
    const int*   adj1        = (const int*)d_in[2];
    const int*   node2_pos   = (const int*)d_in[3];
    const int*   adj2        = (const int*)d_in[4];
    const float* W1          = (const float*)d_in[5];
    const float* b1          = (const float*)d_in[6];
    const float* W2          = (const float*)d_in[7];
    const float* b2          = (const float*)d_in[8];
    float* out = (float*)d_out;

    __half* ft0 = (__half*)d_ws;                  // CN0*CD fp16 = 25.6 MB
    __half* ft1 = ft0 + (size_t)CN0 * CD;         // CN1*CD fp16 = 12.8 MB

    int t1 = CN0 * 8;
    k_lv0<<<(t1 + 255) / 256, 256, 0, stream>>>(node_feats, ft0);
    k_conv<false, __half, REP_C1><<<2048, 256, 0, stream>>>(ft0, node_l1_ids, adj1, W1, b1, ft1, CN1);
    k_conv<true, float, REP_C2><<<2048, 256, 0, stream>>>(ft1, node2_pos, adj2, W2, b2, out, CN2);
}

// Round 9
// 376.212 us; speedup vs baseline: 13.1948x; 3.0881x over previous
//
#include <hip/hip_runtime.h>
#include <hip/hip_fp16.h>

#define CN0 200000
#define CN1 100000
#define CN2 50000
#define CM 16
#define CVL 32
#define CK 32
#define CD 64
#define CEPS 1e-12f

typedef float f32x2 __attribute__((ext_vector_type(2)));
typedef _Float16 half2_t __attribute__((ext_vector_type(2)));

union H4 { __half2 h2[2]; uint2 u; };
union U64H4 { unsigned long long u; _Float16 h[4]; };

// Stage 0: ft_lv0[n] = concat(sum_m x, 0.5*(s^2 - sum x^2)), fp16 out.
// 8 threads per node; at HBM floor (~73 us).
__global__ void k_lv0(const float* __restrict__ x, __half* __restrict__ ft0) {
    int t = blockIdx.x * blockDim.x + threadIdx.x;
    int n = t >> 3;
    int q = t & 7;
    if (n >= CN0) return;
    const float4* xp = reinterpret_cast<const float4*>(x + (size_t)n * (CM * CVL)) + q;
    float4 s = make_float4(0.f, 0.f, 0.f, 0.f);
    float4 sq = make_float4(0.f, 0.f, 0.f, 0.f);
#pragma unroll
    for (int m = 0; m < CM; ++m) {
        float4 v = xp[m * (CVL / 4)];
        s.x += v.x; s.y += v.y; s.z += v.z; s.w += v.w;
        sq.x += v.x * v.x; sq.y += v.y * v.y; sq.z += v.z * v.z; sq.w += v.w * v.w;
    }
    float4 cr;
    cr.x = 0.5f * (s.x * s.x - sq.x);
    cr.y = 0.5f * (s.y * s.y - sq.y);
    cr.z = 0.5f * (s.z * s.z - sq.z);
    cr.w = 0.5f * (s.w * s.w - sq.w);
    uint2* orow = reinterpret_cast<uint2*>(ft0 + (size_t)n * CD);
    H4 pa, pb;
    pa.h2[0] = __floats2half2_rn(s.x, s.y);
    pa.h2[1] = __floats2half2_rn(s.z, s.w);
    pb.h2[0] = __floats2half2_rn(cr.x, cr.y);
    pb.h2[1] = __floats2half2_rn(cr.z, cr.w);
    orow[q] = pa.u;
    orow[8 + q] = pb.u;
}

// Conv v2 (VALU-diet): wave owns P=4 nodes. Gather: lane=(g=lane>>4 row-group,
// h=lane&15 dim-quad), 8 uint2 feature loads + 8 adj dwords + self; 2-level
// shfl reduce; immediate accumulate (NO payload arrays -> no scratch).
// c staged transposed in LDS cs[wave][row 0..127][p 0..3] so the matmul
// broadcast is ONE uniform ds_read_b128 per row feeding all 4 nodes (LDS pipe,
// not VALU readlane). W packed 4xf16 per (row-quad, j) -> per-lane ds_read_b64.
// FMAs paired over nodes via f32x2 (v_pk_fma_f32). f32 c/acc (fp16 c overflows
// at level 2); fp16 W/features as round 6 (absmax 3.9e-3 proven).
// nNodes % 16 == 0 for both levels -> no tail handling.
template<bool NORM, typename OutT>
__global__ void __launch_bounds__(256)
k_conv(const __half* __restrict__ ftin,
       const int* __restrict__ ids,
       const int* __restrict__ adj,
       const float* __restrict__ W,
       const float* __restrict__ bias,
       OutT* __restrict__ ftout,
       int nNodes) {
    __shared__ unsigned long long Wq[32][CD];        // 16 KiB: W[4t..4t+3][j] f16x4
    __shared__ __align__(16) float cs[4][128][4];    // 8 KiB: [wave][row][p]
    __shared__ float bl[CD];
    for (int idx = threadIdx.x; idx < 32 * CD; idx += blockDim.x) {
        const int t = idx >> 6, j = idx & 63;
        U64H4 u;
#pragma unroll
        for (int d = 0; d < 4; ++d) u.h[d] = (_Float16)W[(4 * t + d) * CD + j];
        Wq[t][j] = u.u;
    }
    if (threadIdx.x < CD) bl[threadIdx.x] = bias[threadIdx.x];
    __syncthreads();

    const int lane = threadIdx.x & 63;
    const int wv = __builtin_amdgcn_readfirstlane(threadIdx.x >> 6);
    const int g = lane >> 4;   // row-group 0..3
    const int h = lane & 15;   // dim-quad (dims 4h..4h+3)
    const int nB = nNodes >> 4;  // exact: 100000/16, 50000/16

    for (int b = blockIdx.x; b < nB; b += gridDim.x) {
        const int base = __builtin_amdgcn_readfirstlane(b * 16 + wv * 4);
        // ---- gather + c staging (per node, short lifetimes) ----
#pragma unroll
        for (int p = 0; p < 4; ++p) {
            const int n = base + p;           // wave-uniform
            const int id = ids[n];            // s_load
            const uint2 sv = *reinterpret_cast<const uint2*>(
                ftin + ((size_t)id << 6) + (h << 2));
            const int* arow = adj + (size_t)n * CK;  // uniform base
            float p0 = 0.f, p1 = 0.f, p2 = 0.f, p3 = 0.f;
#pragma unroll
            for (int t = 0; t < 8; ++t) {
                const int r = arow[4 * t + g];       // per-lane dword, imm offset
                const uint2 f = *reinterpret_cast<const uint2*>(
                    ftin + ((size_t)r << 6) + (h << 2));
                const half2_t lo = __builtin_bit_cast(half2_t, f.x);
                const half2_t hi = __builtin_bit_cast(half2_t, f.y);
                p0 += (float)lo.x; p1 += (float)lo.y;
                p2 += (float)hi.x; p3 += (float)hi.y;
            }
            p0 += __shfl_xor(p0, 16); p0 += __shfl_xor(p0, 32);
            p1 += __shfl_xor(p1, 16); p1 += __shfl_xor(p1, 32);
            p2 += __shfl_xor(p2, 16); p2 += __shfl_xor(p2, 32);
            p3 += __shfl_xor(p3, 16); p3 += __shfl_xor(p3, 32);
            const half2_t slo = __builtin_bit_cast(half2_t, sv.x);
            const half2_t shi = __builtin_bit_cast(half2_t, sv.y);
            // lane's assigned row within its quad: d == g (cndmask selects)
            const float pg = (g & 2) ? ((g & 1) ? p3 : p2) : ((g & 1) ? p1 : p0);
            const float sg = (g & 2) ? ((g & 1) ? (float)shi.y : (float)shi.x)
                                     : ((g & 1) ? (float)slo.y : (float)slo.x);
            const int row = (h << 2) + g;     // 0..63, each lane a distinct row
            cs[wv][row][p] = sg + pg;         // c0 rows 0..63
            cs[wv][64 + row][p] = sg * pg;    // c1 rows 64..127
        }
        // same-wave ds_write -> ds_read: compiler inserts lgkmcnt; no barrier
        // (each wave uses its own cs[wv] slice).
        // ---- matmul: out[j] = b[j] + sum_i c[i]*W[i][j]; lane = j ----
        f32x2 a01 = {0.f, 0.f}, a23 = {0.f, 0.f};
#pragma unroll
        for (int t = 0; t < 32; ++t) {
            const U64H4 wq = {Wq[t][lane]};   // per-lane b64 (4 f16 rows)
#pragma unroll
            for (int d = 0; d < 4; ++d) {
                const float4 cv = *reinterpret_cast<const float4*>(
                    &cs[wv][4 * t + d][0]);   // uniform-addr b128 broadcast
                const float wf = (float)wq.h[d];
                const f32x2 c01 = {cv.x, cv.y};
                const f32x2 c23 = {cv.z, cv.w};
                a01 += c01 * wf;              // v_pk_fma_f32
                a23 += c23 * wf;
            }
        }
        // ---- epilogue ----
        const float bj = bl[lane];
        const float zz[4] = {a01.x, a01.y, a23.x, a23.y};
#pragma unroll
        for (int p = 0; p < 4; ++p) {
            float z = fmaxf(zz[p] + bj, 0.f);
            if (NORM) {
                float ss = z * z;
#pragma unroll
                for (int off = 32; off >= 1; off >>= 1) ss += __shfl_xor(ss, off);
                const float nrm = fmaxf(sqrtf(ss), CEPS);
                z = z / nrm;
            }
            ftout[(size_t)(base + p) * CD + lane] = (OutT)z;
        }
    }
}

extern "C" void kernel_launch(void* const* d_in, const int* in_sizes, int n_in,
                              void* d_out, int out_size, void* d_ws, size_t ws_size,
                              hipStream_t stream) {
    const float* node_feats  = (const float*)d_in[0];
    const int*   node_l1_ids = (const int*)d_in[1];
    const int*   adj1        = (const int*)d_in[2];
    const int*   node2_pos   = (const int*)d_in[3];
    const int*   adj2        = (const int*)d_in[4];
    const float* W1          = (const float*)d_in[5];
    const float* b1          = (const float*)d_in[6];
    const float* W2          = (const float*)d_in[7];
    const float* b2          = (const float*)d_in[8];
    float* out = (float*)d_out;

    __half* ft0 = (__half*)d_ws;                  // CN0*CD fp16 = 25.6 MB
    __half* ft1 = ft0 + (size_t)CN0 * CD;         // CN1*CD fp16 = 12.8 MB

    int t1 = CN0 * 8;
    k_lv0<<<(t1 + 255) / 256, 256, 0, stream>>>(node_feats, ft0);
    k_conv<false, __half><<<2048, 256, 0, stream>>>(ft0, node_l1_ids, adj1, W1, b1, ft1, CN1);
    k_conv<true, float><<<2048, 256, 0, stream>>>(ft1, node2_pos, adj2, W2, b2, out, CN2);
}

// Round 10
// 187.630 us; speedup vs baseline: 26.4567x; 2.0051x over previous
//
#include <hip/hip_runtime.h>
#include <hip/hip_fp16.h>

#define CN0 200000
#define CN1 100000
#define CN2 50000
#define CM 16
#define CVL 32
#define CK 32
#define CD 64
#define CEPS 1e-12f

typedef _Float16 half2_t __attribute__((ext_vector_type(2)));
typedef short bf16x8 __attribute__((ext_vector_type(8)));
typedef float f32x4 __attribute__((ext_vector_type(4)));

union H4 { __half2 h2[2]; uint2 u; };

__device__ __forceinline__ uint f32_to_bf16(float f) {
    uint u = __builtin_bit_cast(uint, f);
    return (u + 0x7fffu + ((u >> 16) & 1u)) >> 16;   // RNE
}

// Stage 0: ft_lv0[n] = concat(sum_m x, 0.5*(s^2 - sum x^2)), fp16 out.
// 8 threads/node; at HBM floor (~73 us).
__global__ void k_lv0(const float* __restrict__ x, __half* __restrict__ ft0) {
    int t = blockIdx.x * blockDim.x + threadIdx.x;
    int n = t >> 3;
    int q = t & 7;
    if (n >= CN0) return;
    const float4* xp = reinterpret_cast<const float4*>(x + (size_t)n * (CM * CVL)) + q;
    float4 s = make_float4(0.f, 0.f, 0.f, 0.f);
    float4 sq = make_float4(0.f, 0.f, 0.f, 0.f);
#pragma unroll
    for (int m = 0; m < CM; ++m) {
        float4 v = xp[m * (CVL / 4)];
        s.x += v.x; s.y += v.y; s.z += v.z; s.w += v.w;
        sq.x += v.x * v.x; sq.y += v.y * v.y; sq.z += v.z * v.z; sq.w += v.w * v.w;
    }
    float4 cr;
    cr.x = 0.5f * (s.x * s.x - sq.x);
    cr.y = 0.5f * (s.y * s.y - sq.y);
    cr.z = 0.5f * (s.z * s.z - sq.z);
    cr.w = 0.5f * (s.w * s.w - sq.w);
    uint2* orow = reinterpret_cast<uint2*>(ft0 + (size_t)n * CD);
    H4 pa, pb;
    pa.h2[0] = __floats2half2_rn(s.x, s.y);
    pa.h2[1] = __floats2half2_rn(s.z, s.w);
    pb.h2[0] = __floats2half2_rn(cr.x, cr.y);
    pb.h2[1] = __floats2half2_rn(cr.z, cr.w);
    orow[q] = pa.u;
    orow[8 + q] = pb.u;
}

// One-time W -> bf16 B-fragment transpose for mfma_f32_16x16x32_bf16.
// Entry e = f*64 + l, f = t*4 + c: 8 bf16 = W[c*32 + (l>>4)*8 + j][t*16 + (l&15)].
__global__ void k_prepw(const float* __restrict__ W1, const float* __restrict__ W2,
                        ushort* __restrict__ Wf1, ushort* __restrict__ Wf2) {
    const float* W = blockIdx.x ? W2 : W1;
    ushort* Wf = blockIdx.x ? Wf2 : Wf1;
    for (int e = threadIdx.x; e < 1024; e += blockDim.x) {
        const int f = e >> 6, l = e & 63;
        const int t = f >> 2, c = f & 3;
        const int n = (t << 4) + (l & 15);
        const int k0 = (c << 5) + ((l >> 4) << 3);
        uint w[8];
#pragma unroll
        for (int j = 0; j < 8; ++j) w[j] = f32_to_bf16(W[(k0 + j) * CD + n]);
        uint4 v;
        v.x = w[0] | (w[1] << 16); v.y = w[2] | (w[3] << 16);
        v.z = w[4] | (w[5] << 16); v.w = w[6] | (w[7] << 16);
        reinterpret_cast<uint4*>(Wf)[e] = v;
    }
}

// Conv via MFMA: wave owns 16 nodes. Gather (2 dims/lane: h=lane&31 -> dims
// 2h,2h+1; g=lane>>5 -> neighbor rows 2t+g), immediate f32 accumulate, one
// shfl_xor(32) combine. c packed to bf16 (v_cvt_pk_bf16_f32) and staged as a
// 16x128 A-tile in XOR-swizzled LDS (g=0 lanes write c0 rows, g=1 write c1).
// Matmul: 4 ds_read_b128 A-frags x 4 B-tiles = 16 MFMA per 16 nodes. W held
// as pre-transposed bf16 B-fragments in LDS. f32 pool/c (no fp16 overflow).
template<bool NORM, typename OutT>
__global__ void __launch_bounds__(256)
k_conv(const __half* __restrict__ ftin, const int* __restrict__ ids,
       const int* __restrict__ adj, const ushort* __restrict__ Wf,
       const float* __restrict__ bias, OutT* __restrict__ ftout, int nNodes)
{
    __shared__ char Albs[4 * 4096];   // per-wave 16x128 bf16 A-tile, swizzled
    __shared__ uint4 Bfr[1024];       // 16 KiB B-fragments
    __shared__ float bl[CD];
    for (int i = threadIdx.x; i < 1024; i += blockDim.x)
        Bfr[i] = reinterpret_cast<const uint4*>(Wf)[i];
    if (threadIdx.x < CD) bl[threadIdx.x] = bias[threadIdx.x];
    __syncthreads();

    const int lane = threadIdx.x & 63;
    const int wv = __builtin_amdgcn_readfirstlane(threadIdx.x >> 6);
    const int g = lane >> 5;
    const int h = lane & 31;
    // write-side: this lane writes k-pair kw (c0 rows if g=0, c1 rows if g=1)
    const int kw = g ? (CD + 2 * h) : (2 * h);
    const int wr_lane = ((kw >> 3) << 4) | ((kw & 7) << 1);  // pre-swizzle byte
    char* Aw = Albs + (wv << 12);
    // read-side (MFMA A-frag): lane -> row m = lane&15, k-group lp = lane>>4
    const int mrow = lane & 15;
    const int lp = lane >> 4;
    const int mm7 = mrow & 7;
    const float b0 = bl[mrow], b1 = bl[16 + mrow], b2 = bl[32 + mrow], b3 = bl[48 + mrow];

    const int nB = (nNodes + 63) >> 6;
    for (int b = blockIdx.x; b < nB; b += gridDim.x) {
        const int base = __builtin_amdgcn_readfirstlane((b << 6) + (wv << 4));
        // ---- gather + A-tile staging, 16 nodes ----
#pragma unroll 2
        for (int p = 0; p < 16; ++p) {
            const int nn = base + p;
            const int n = nn < nNodes ? nn : nNodes - 1;   // clamp; stores guarded
            const int id = ids[n];                          // uniform -> s_load
            const uint sv = *reinterpret_cast<const uint*>(
                ftin + ((size_t)id << 6) + (h << 1));
            const int* arow = adj + (size_t)n * CK;
            float px = 0.f, py = 0.f;
#pragma unroll
            for (int t = 0; t < 16; ++t) {
                const int r = arow[2 * t + g];
                const uint fv = *reinterpret_cast<const uint*>(
                    ftin + ((size_t)r << 6) + (h << 1));
                const half2_t v = __builtin_bit_cast(half2_t, fv);
                px += (float)v.x; py += (float)v.y;
            }
            px += __shfl_xor(px, 32);
            py += __shfl_xor(py, 32);
            const half2_t s = __builtin_bit_cast(half2_t, sv);
            const float s0 = (float)s.x, s1 = (float)s.y;
            const float wx = g ? (s0 * px) : (s0 + px);
            const float wy = g ? (s1 * py) : (s1 + py);
            uint pk;
            asm("v_cvt_pk_bf16_f32 %0, %1, %2" : "=v"(pk) : "v"(wx), "v"(wy));
            *reinterpret_cast<uint*>(
                Aw + ((p << 8) + (wr_lane ^ ((p & 7) << 4)))) = pk;
        }
        // same-wave ds_write -> ds_read: lgkmcnt ordering, no barrier needed.
        // ---- MFMA: D[16 nodes][64] = A[16][128] x W[128][64] + b ----
        f32x4 acc0 = {b0, b0, b0, b0}, acc1 = {b1, b1, b1, b1};
        f32x4 acc2 = {b2, b2, b2, b2}, acc3 = {b3, b3, b3, b3};
#pragma unroll
        for (int c = 0; c < 4; ++c) {
            const int gran = ((c << 2) | lp) ^ mm7;
            const bf16x8 a = *reinterpret_cast<const bf16x8*>(
                Aw + (mrow << 8) + (gran << 4));
            acc0 = __builtin_amdgcn_mfma_f32_16x16x32_bf16(
                a, __builtin_bit_cast(bf16x8, Bfr[(0 * 4 + c) * 64 + lane]), acc0, 0, 0, 0);
            acc1 = __builtin_amdgcn_mfma_f32_16x16x32_bf16(
                a, __builtin_bit_cast(bf16x8, Bfr[(1 * 4 + c) * 64 + lane]), acc1, 0, 0, 0);
            acc2 = __builtin_amdgcn_mfma_f32_16x16x32_bf16(
                a, __builtin_bit_cast(bf16x8, Bfr[(2 * 4 + c) * 64 + lane]), acc2, 0, 0, 0);
            acc3 = __builtin_amdgcn_mfma_f32_16x16x32_bf16(
                a, __builtin_bit_cast(bf16x8, Bfr[(3 * 4 + c) * 64 + lane]), acc3, 0, 0, 0);
        }
        // ---- epilogue: relu (+ norm), store. C layout: col=lane&15,
        // row (node within tile) = lp*4 + reg ----
        float z0[4], z1[4], z2[4], z3[4];
#pragma unroll
        for (int r = 0; r < 4; ++r) {
            z0[r] = fmaxf(acc0[r], 0.f);
            z1[r] = fmaxf(acc1[r], 0.f);
            z2[r] = fmaxf(acc2[r], 0.f);
            z3[r] = fmaxf(acc3[r], 0.f);
        }
        if (NORM) {
#pragma unroll
            for (int r = 0; r < 4; ++r) {
                float ss = z0[r] * z0[r] + z1[r] * z1[r] + z2[r] * z2[r] + z3[r] * z3[r];
                ss += __shfl_xor(ss, 1);
                ss += __shfl_xor(ss, 2);
                ss += __shfl_xor(ss, 4);
                ss += __shfl_xor(ss, 8);
                const float inv = 1.0f / fmaxf(sqrtf(ss), CEPS);
                z0[r] *= inv; z1[r] *= inv; z2[r] *= inv; z3[r] *= inv;
            }
        }
#pragma unroll
        for (int r = 0; r < 4; ++r) {
            const int node = base + (lp << 2) + r;
            if (node < nNodes) {
                OutT* orow = ftout + (size_t)node * CD + mrow;
                orow[0]  = (OutT)z0[r];
                orow[16] = (OutT)z1[r];
                orow[32] = (OutT)z2[r];
                orow[48] = (OutT)z3[r];
            }
        }
    }
}

extern "C" void kernel_launch(void* const* d_in, const int* in_sizes, int n_in,
                              void* d_out, int out_size, void* d_ws, size_t ws_size,
                              hipStream_t stream) {
    const float* node_feats  = (const float*)d_in[0];
    const int*   node_l1_ids = (const int*)d_in[1];
    const int*   adj1        = (const int*)d_in[2];
    const int*   node2_pos   = (const int*)d_in[3];
    const int*   adj2        = (const int*)d_in[4];
    const float* W1          = (const float*)d_in[5];
    const float* b1          = (const float*)d_in[6];
    const float* W2          = (const float*)d_in[7];
    const float* b2          = (const float*)d_in[8];
    float* out = (float*)d_out;

    __half* ft0 = (__half*)d_ws;                   // 25.6 MB
    __half* ft1 = ft0 + (size_t)CN0 * CD;          // 12.8 MB
    ushort* Wf1 = (ushort*)(ft1 + (size_t)CN1 * CD);  // 16 KB
    ushort* Wf2 = Wf1 + 8192;                          // 16 KB

    k_prepw<<<2, 256, 0, stream>>>(W1, W2, Wf1, Wf2);
    int t1 = CN0 * 8;
    k_lv0<<<(t1 + 255) / 256, 256, 0, stream>>>(node_feats, ft0);
    const int nB1 = (CN1 + 63) / 64;
    const int nB2 = (CN2 + 63) / 64;
    k_conv<false, __half><<<nB1, 256, 0, stream>>>(ft0, node_l1_ids, adj1, Wf1, b1, ft1, CN1);
    k_conv<true, float><<<nB2, 256, 0, stream>>>(ft1, node2_pos, adj2, Wf2, b2, out, CN2);
}

// Round 11
// 184.898 us; speedup vs baseline: 26.8476x; 1.0148x over previous
//
#include <hip/hip_runtime.h>
#include <hip/hip_fp16.h>

#define CN0 200000
#define CN1 100000
#define CN2 50000
#define CM 16
#define CVL 32
#define CK 32
#define CD 64
#define CEPS 1e-12f

typedef _Float16 half2_t __attribute__((ext_vector_type(2)));
typedef short bf16x8 __attribute__((ext_vector_type(8)));
typedef float f32x4 __attribute__((ext_vector_type(4)));

union H4 { __half2 h2[2]; uint2 u; };

__device__ __forceinline__ uint f32_to_bf16(float f) {
    uint u = __builtin_bit_cast(uint, f);
    return (u + 0x7fffu + ((u >> 16) & 1u)) >> 16;   // RNE
}

__device__ __forceinline__ uint2 pk_add_h2x2(uint2 a, uint2 b) {
    uint2 r;
    r.x = __builtin_bit_cast(uint, __builtin_bit_cast(half2_t, a.x) +
                                   __builtin_bit_cast(half2_t, b.x));
    r.y = __builtin_bit_cast(uint, __builtin_bit_cast(half2_t, a.y) +
                                   __builtin_bit_cast(half2_t, b.y));
    return r;
}

// Stage 0: ft_lv0[n] = concat(sum_m x, 0.5*(s^2 - sum x^2)), fp16 out.
// 8 threads/node; at HBM floor (~73 us).
__global__ void k_lv0(const float* __restrict__ x, __half* __restrict__ ft0) {
    int t = blockIdx.x * blockDim.x + threadIdx.x;
    int n = t >> 3;
    int q = t & 7;
    if (n >= CN0) return;
    const float4* xp = reinterpret_cast<const float4*>(x + (size_t)n * (CM * CVL)) + q;
    float4 s = make_float4(0.f, 0.f, 0.f, 0.f);
    float4 sq = make_float4(0.f, 0.f, 0.f, 0.f);
#pragma unroll
    for (int m = 0; m < CM; ++m) {
        float4 v = xp[m * (CVL / 4)];
        s.x += v.x; s.y += v.y; s.z += v.z; s.w += v.w;
        sq.x += v.x * v.x; sq.y += v.y * v.y; sq.z += v.z * v.z; sq.w += v.w * v.w;
    }
    float4 cr;
    cr.x = 0.5f * (s.x * s.x - sq.x);
    cr.y = 0.5f * (s.y * s.y - sq.y);
    cr.z = 0.5f * (s.z * s.z - sq.z);
    cr.w = 0.5f * (s.w * s.w - sq.w);
    uint2* orow = reinterpret_cast<uint2*>(ft0 + (size_t)n * CD);
    H4 pa, pb;
    pa.h2[0] = __floats2half2_rn(s.x, s.y);
    pa.h2[1] = __floats2half2_rn(s.z, s.w);
    pb.h2[0] = __floats2half2_rn(cr.x, cr.y);
    pb.h2[1] = __floats2half2_rn(cr.z, cr.w);
    orow[q] = pa.u;
    orow[8 + q] = pb.u;
}

// One-time W -> bf16 B-fragment transpose for mfma_f32_16x16x32_bf16.
__global__ void k_prepw(const float* __restrict__ W1, const float* __restrict__ W2,
                        ushort* __restrict__ Wf1, ushort* __restrict__ Wf2) {
    const float* W = blockIdx.x ? W2 : W1;
    ushort* Wf = blockIdx.x ? Wf2 : Wf1;
    for (int e = threadIdx.x; e < 1024; e += blockDim.x) {
        const int f = e >> 6, l = e & 63;
        const int t = f >> 2, c = f & 3;
        const int n = (t << 4) + (l & 15);
        const int k0 = (c << 5) + ((l >> 4) << 3);
        uint w[8];
#pragma unroll
        for (int j = 0; j < 8; ++j) w[j] = f32_to_bf16(W[(k0 + j) * CD + n]);
        uint4 v;
        v.x = w[0] | (w[1] << 16); v.y = w[2] | (w[3] << 16);
        v.z = w[4] | (w[5] << 16); v.w = w[6] | (w[7] << 16);
        reinterpret_cast<uint4*>(Wf)[e] = v;
    }
}

// Conv via MFMA, gather on a VALU diet: wave owns 16 nodes. lane ->
// (g=lane>>4: 8 neighbors 4t+g; h=lane&15: dims 4h..4h+3). 8 uint2 feature
// loads summed by a fp16 pairwise tree (v_pk_add_f16; 8-way partial sums
// bounded ~8x entry < fp16 max), converted to f32 for the cross-group
// shfl reduce and the c0/c1 compute (c1 overflows fp16). g<2 lanes pack
// 4 bf16 and ds_write_b64 the swizzled 16x128 A-tile; 16 MFMAs per 16
// nodes against pre-transposed bf16 W fragments.
template<bool NORM, typename OutT>
__global__ void __launch_bounds__(256)
k_conv(const __half* __restrict__ ftin, const int* __restrict__ ids,
       const int* __restrict__ adj, const ushort* __restrict__ Wf,
       const float* __restrict__ bias, OutT* __restrict__ ftout, int nNodes)
{
    __shared__ char Albs[4 * 4096];   // per-wave 16x128 bf16 A-tile, swizzled
    __shared__ uint4 Bfr[1024];       // 16 KiB B-fragments
    __shared__ float bl[CD];
    for (int i = threadIdx.x; i < 1024; i += blockDim.x)
        Bfr[i] = reinterpret_cast<const uint4*>(Wf)[i];
    if (threadIdx.x < CD) bl[threadIdx.x] = bias[threadIdx.x];
    __syncthreads();

    const int lane = threadIdx.x & 63;
    const int wv = __builtin_amdgcn_readfirstlane(threadIdx.x >> 6);
    const int g = lane >> 4;   // neighbor-group 0..3
    const int h = lane & 15;   // dim-quad (dims 4h..4h+3)
    char* Aw = Albs + (wv << 12);
    // write-side constants (only g<2 lanes store): k-quad kq = g*64 + 4h
    const int kq = ((g & 1) << 6) + (h << 2);
    const int wbyte = ((kq >> 3) << 4) | ((kq & 7) << 1);   // b64-aligned
    // read-side (MFMA A-frag): row m = lane&15, k-group lp = lane>>4
    const int mrow = lane & 15;
    const int lp = lane >> 4;
    const int mm7 = mrow & 7;
    const float b0 = bl[mrow], b1 = bl[16 + mrow], b2 = bl[32 + mrow], b3 = bl[48 + mrow];

    const int nB = (nNodes + 63) >> 6;
    for (int b = blockIdx.x; b < nB; b += gridDim.x) {
        const int base = __builtin_amdgcn_readfirstlane((b << 6) + (wv << 4));
        // ---- gather + A-tile staging, 16 nodes ----
#pragma unroll 2
        for (int p = 0; p < 16; ++p) {
            const int nn = base + p;
            const int n = nn < nNodes ? nn : nNodes - 1;   // clamp; stores guarded
            const int id = ids[n];                          // uniform -> s_load
            const uint2 sv = *reinterpret_cast<const uint2*>(
                ftin + ((size_t)id << 6) + (h << 2));
            const int* arow = adj + (size_t)n * CK;
            auto FL = [&](int t) -> uint2 {
                const int r = arow[4 * t + g];
                return *reinterpret_cast<const uint2*>(
                    ftin + ((size_t)r << 6) + (h << 2));
            };
            const uint2 f0 = FL(0), f1 = FL(1), f2 = FL(2), f3 = FL(3);
            const uint2 s01 = pk_add_h2x2(f0, f1);
            const uint2 s23 = pk_add_h2x2(f2, f3);
            const uint2 f4 = FL(4), f5 = FL(5), f6 = FL(6), f7 = FL(7);
            const uint2 s45 = pk_add_h2x2(f4, f5);
            const uint2 s67 = pk_add_h2x2(f6, f7);
            const uint2 q0 = pk_add_h2x2(s01, s23);
            const uint2 q1 = pk_add_h2x2(s45, s67);
            const uint2 tt = pk_add_h2x2(q0, q1);   // 8-way fp16 partial sums
            const half2_t tl = __builtin_bit_cast(half2_t, tt.x);
            const half2_t th = __builtin_bit_cast(half2_t, tt.y);
            float p0 = (float)tl.x, p1 = (float)tl.y;
            float p2 = (float)th.x, p3 = (float)th.y;
            p0 += __shfl_xor(p0, 16); p1 += __shfl_xor(p1, 16);
            p2 += __shfl_xor(p2, 16); p3 += __shfl_xor(p3, 16);
            p0 += __shfl_xor(p0, 32); p1 += __shfl_xor(p1, 32);
            p2 += __shfl_xor(p2, 32); p3 += __shfl_xor(p3, 32);
            const half2_t sl = __builtin_bit_cast(half2_t, sv.x);
            const half2_t sh = __builtin_bit_cast(half2_t, sv.y);
            const float s0 = (float)sl.x, s1 = (float)sl.y;
            const float s2 = (float)sh.x, s3 = (float)sh.y;
            const bool mul = (g & 1);                       // g1/g3: "*" rows
            const float w0 = mul ? s0 * p0 : s0 + p0;
            const float w1 = mul ? s1 * p1 : s1 + p1;
            const float w2 = mul ? s2 * p2 : s2 + p2;
            const float w3 = mul ? s3 * p3 : s3 + p3;
            uint pk0, pk1;
            asm("v_cvt_pk_bf16_f32 %0, %1, %2" : "=v"(pk0) : "v"(w0), "v"(w1));
            asm("v_cvt_pk_bf16_f32 %0, %1, %2" : "=v"(pk1) : "v"(w2), "v"(w3));
            if (g < 2) {
                uint2 wq; wq.x = pk0; wq.y = pk1;
                *reinterpret_cast<uint2*>(
                    Aw + ((p << 8) + (wbyte ^ ((p & 7) << 4)))) = wq;
            }
        }
        // same-wave ds_write -> ds_read: lgkmcnt ordering, no barrier needed.
        // ---- MFMA: D[16 nodes][64] = A[16][128] x W[128][64] + b ----
        f32x4 acc0 = {b0, b0, b0, b0}, acc1 = {b1, b1, b1, b1};
        f32x4 acc2 = {b2, b2, b2, b2}, acc3 = {b3, b3, b3, b3};
#pragma unroll
        for (int c = 0; c < 4; ++c) {
            const int gran = ((c << 2) | lp) ^ mm7;
            const bf16x8 a = *reinterpret_cast<const bf16x8*>(
                Aw + (mrow << 8) + (gran << 4));
            acc0 = __builtin_amdgcn_mfma_f32_16x16x32_bf16(
                a, __builtin_bit_cast(bf16x8, Bfr[(0 * 4 + c) * 64 + lane]), acc0, 0, 0, 0);
            acc1 = __builtin_amdgcn_mfma_f32_16x16x32_bf16(
                a, __builtin_bit_cast(bf16x8, Bfr[(1 * 4 + c) * 64 + lane]), acc1, 0, 0, 0);
            acc2 = __builtin_amdgcn_mfma_f32_16x16x32_bf16(
                a, __builtin_bit_cast(bf16x8, Bfr[(2 * 4 + c) * 64 + lane]), acc2, 0, 0, 0);
            acc3 = __builtin_amdgcn_mfma_f32_16x16x32_bf16(
                a, __builtin_bit_cast(bf16x8, Bfr[(3 * 4 + c) * 64 + lane]), acc3, 0, 0, 0);
        }
        // ---- epilogue: relu (+ norm), store. C layout: col=lane&15,
        // node-in-tile = lp*4 + reg ----
        float z0[4], z1[4], z2[4], z3[4];
#pragma unroll
        for (int r = 0; r < 4; ++r) {
            z0[r] = fmaxf(acc0[r], 0.f);
            z1[r] = fmaxf(acc1[r], 0.f);
            z2[r] = fmaxf(acc2[r], 0.f);
            z3[r] = fmaxf(acc3[r], 0.f);
        }
        if (NORM) {
#pragma unroll
            for (int r = 0; r < 4; ++r) {
                float ss = z0[r] * z0[r] + z1[r] * z1[r] + z2[r] * z2[r] + z3[r] * z3[r];
                ss += __shfl_xor(ss, 1);
                ss += __shfl_xor(ss, 2);
                ss += __shfl_xor(ss, 4);
                ss += __shfl_xor(ss, 8);
                const float inv = 1.0f / fmaxf(sqrtf(ss), CEPS);
                z0[r] *= inv; z1[r] *= inv; z2[r] *= inv; z3[r] *= inv;
            }
        }
#pragma unroll
        for (int r = 0; r < 4; ++r) {
            const int node = base + (lp << 2) + r;
            if (node < nNodes) {
                OutT* orow = ftout + (size_t)node * CD + mrow;
                orow[0]  = (OutT)z0[r];
                orow[16] = (OutT)z1[r];
                orow[32] = (OutT)z2[r];
                orow[48] = (OutT)z3[r];
            }
        }
    }
}

extern "C" void kernel_launch(void* const* d_in, const int* in_sizes, int n_in,
                              void* d_out, int out_size, void* d_ws, size_t ws_size,
                              hipStream_t stream) {
    const float* node_feats  = (const float*)d_in[0];
    const int*   node_l1_ids = (const int*)d_in[1];
    const int*   adj1        = (const int*)d_in[2];
    const int*   node2_pos   = (const int*)d_in[3];
    const int*   adj2        = (const int*)d_in[4];
    const float* W1          = (const float*)d_in[5];
    const float* b1          = (const float*)d_in[6];
    const float* W2          = (const float*)d_in[7];
    const float* b2          = (const float*)d_in[8];
    float* out = (float*)d_out;

    __half* ft0 = (__half*)d_ws;                   // 25.6 MB
    __half* ft1 = ft0 + (size_t)CN0 * CD;          // 12.8 MB
    ushort* Wf1 = (ushort*)(ft1 + (size_t)CN1 * CD);  // 16 KB
    ushort* Wf2 = Wf1 + 8192;                          // 16 KB

    k_prepw<<<2, 256, 0, stream>>>(W1, W2, Wf1, Wf2);
    int t1 = CN0 * 8;
    k_lv0<<<(t1 + 255) / 256, 256, 0, stream>>>(node_feats, ft0);
    const int nB1 = (CN1 + 63) / 64;
    const int nB2 = (CN2 + 63) / 64;
    k_conv<false, __half><<<nB1, 256, 0, stream>>>(ft0, node_l1_ids, adj1, Wf1, b1, ft1, CN1);
    k_conv<true, float><<<nB2, 256, 0, stream>>>(ft1, node2_pos, adj2, Wf2, b2, out, CN2);
}

// Round 12
// 179.366 us; speedup vs baseline: 27.6756x; 1.0308x over previous
//
#include <hip/hip_runtime.h>
#include <hip/hip_fp16.h>

#define CN0 200000
#define CN1 100000
#define CN2 50000
#define CM 16
#define CVL 32
#define CK 32
#define CD 64
#define CEPS 1e-12f

typedef _Float16 half2_t __attribute__((ext_vector_type(2)));
typedef short bf16x8 __attribute__((ext_vector_type(8)));
typedef float f32x4 __attribute__((ext_vector_type(4)));

union H4 { __half2 h2[2]; uint2 u; };

__device__ __forceinline__ uint f32_to_bf16(float f) {
    uint u = __builtin_bit_cast(uint, f);
    return (u + 0x7fffu + ((u >> 16) & 1u)) >> 16;   // RNE
}

__device__ __forceinline__ uint2 pk_add_h2x2(uint2 a, uint2 b) {
    uint2 r;
    r.x = __builtin_bit_cast(uint, __builtin_bit_cast(half2_t, a.x) +
                                   __builtin_bit_cast(half2_t, b.x));
    r.y = __builtin_bit_cast(uint, __builtin_bit_cast(half2_t, a.y) +
                                   __builtin_bit_cast(half2_t, b.y));
    return r;
}

// Stage 0: ft_lv0[n] = concat(sum_m x, 0.5*(s^2 - sum x^2)), fp16 out.
// 8 threads/node; at HBM floor (~73 us).
__global__ void k_lv0(const float* __restrict__ x, __half* __restrict__ ft0) {
    int t = blockIdx.x * blockDim.x + threadIdx.x;
    int n = t >> 3;
    int q = t & 7;
    if (n >= CN0) return;
    const float4* xp = reinterpret_cast<const float4*>(x + (size_t)n * (CM * CVL)) + q;
    float4 s = make_float4(0.f, 0.f, 0.f, 0.f);
    float4 sq = make_float4(0.f, 0.f, 0.f, 0.f);
#pragma unroll
    for (int m = 0; m < CM; ++m) {
        float4 v = xp[m * (CVL / 4)];
        s.x += v.x; s.y += v.y; s.z += v.z; s.w += v.w;
        sq.x += v.x * v.x; sq.y += v.y * v.y; sq.z += v.z * v.z; sq.w += v.w * v.w;
    }
    float4 cr;
    cr.x = 0.5f * (s.x * s.x - sq.x);
    cr.y = 0.5f * (s.y * s.y - sq.y);
    cr.z = 0.5f * (s.z * s.z - sq.z);
    cr.w = 0.5f * (s.w * s.w - sq.w);
    uint2* orow = reinterpret_cast<uint2*>(ft0 + (size_t)n * CD);
    H4 pa, pb;
    pa.h2[0] = __floats2half2_rn(s.x, s.y);
    pa.h2[1] = __floats2half2_rn(s.z, s.w);
    pb.h2[0] = __floats2half2_rn(cr.x, cr.y);
    pb.h2[1] = __floats2half2_rn(cr.z, cr.w);
    orow[q] = pa.u;
    orow[8 + q] = pb.u;
}

// One-time W -> bf16 B-fragment transpose for mfma_f32_16x16x32_bf16.
__global__ void k_prepw(const float* __restrict__ W1, const float* __restrict__ W2,
                        ushort* __restrict__ Wf1, ushort* __restrict__ Wf2) {
    const float* W = blockIdx.x ? W2 : W1;
    ushort* Wf = blockIdx.x ? Wf2 : Wf1;
    for (int e = threadIdx.x; e < 1024; e += blockDim.x) {
        const int f = e >> 6, l = e & 63;
        const int t = f >> 2, c = f & 3;
        const int n = (t << 4) + (l & 15);
        const int k0 = (c << 5) + ((l >> 4) << 3);
        uint w[8];
#pragma unroll
        for (int j = 0; j < 8; ++j) w[j] = f32_to_bf16(W[(k0 + j) * CD + n]);
        uint4 v;
        v.x = w[0] | (w[1] << 16); v.y = w[2] | (w[3] << 16);
        v.z = w[4] | (w[5] << 16); v.w = w[6] | (w[7] << 16);
        reinterpret_cast<uint4*>(Wf)[e] = v;
    }
}

// Conv via MFMA, latency-optimized gather: wave owns 16 nodes.
// Pass prologue: ids[cbase..cbase+15] as scalar loads (16 SGPR); the 16
// adj rows (2 KB contiguous) cooperatively loaded per-lane (2x uint4) into
// a per-wave LDS tile -> per-node indices come from ds_read (VGPR), removing
// the SGPR-serialized s_load chain so unroll-4 pipelines 4 nodes of feature
// gathers. No Bfr/bias LDS, no barrier: B-fragments read from global
// (L1/L2-hot) in the MFMA phase; LDS 24.3 KB -> 6 blocks/CU.
// Numerics/layouts identical to the passing round-11 kernel.
template<bool NORM, typename OutT>
__global__ void __launch_bounds__(256)
k_conv(const __half* __restrict__ ftin, const int* __restrict__ ids,
       const int* __restrict__ adj, const ushort* __restrict__ Wf,
       const float* __restrict__ bias, OutT* __restrict__ ftout, int nNodes)
{
    __shared__ char Albs[4 * 4096];   // per-wave 16x128 bf16 A-tile, swizzled
    __shared__ int adjT[4 * 512];     // per-wave 16x32 adjacency tile (8 KiB)

    const int lane = threadIdx.x & 63;
    const int wv = __builtin_amdgcn_readfirstlane(threadIdx.x >> 6);
    const int g = lane >> 4;   // neighbor-group 0..3
    const int h = lane & 15;   // dim-quad (dims 4h..4h+3)
    char* Aw = Albs + (wv << 12);
    int* adjW = adjT + (wv << 9);
    // write-side constants (only g<2 lanes store): k-quad kq = g*64 + 4h
    const int kq = ((g & 1) << 6) + (h << 2);
    const int wbyte = ((kq >> 3) << 4) | ((kq & 7) << 1);   // b64-aligned
    // read-side (MFMA A-frag): row m = lane&15, k-group lp = lane>>4
    const int mrow = lane & 15;
    const int lp = lane >> 4;
    const int mm7 = mrow & 7;
    const float bb0 = bias[mrow], bb1 = bias[16 + mrow];
    const float bb2 = bias[32 + mrow], bb3 = bias[48 + mrow];
    const uint4* Bg = reinterpret_cast<const uint4*>(Wf);

    const int nB = (nNodes + 63) >> 6;
    for (int b = blockIdx.x; b < nB; b += gridDim.x) {
        const int base = __builtin_amdgcn_readfirstlane((b << 6) + (wv << 4));
        const int cbase = __builtin_amdgcn_readfirstlane(
            base < nNodes - 16 ? base : nNodes - 16);   // nNodes % 16 == 0
        // ---- pass prologue: ids (scalar) + adj tile (vector -> LDS) ----
        int idv[16];
#pragma unroll
        for (int p = 0; p < 16; ++p) idv[p] = ids[cbase + p];   // s_loads
        {
            const uint4* src = reinterpret_cast<const uint4*>(adj + ((size_t)cbase << 5));
            uint4* dst = reinterpret_cast<uint4*>(adjW);
            dst[lane] = src[lane];
            dst[64 + lane] = src[64 + lane];
        }
        // ---- gather + A-tile staging, 16 nodes, 4-deep pipelined ----
#pragma unroll 4
        for (int p = 0; p < 16; ++p) {
            const int* arow = adjW + (p << 5);
            const int r0 = arow[g +  0], r1 = arow[g +  4];
            const int r2 = arow[g +  8], r3 = arow[g + 12];
            const int r4 = arow[g + 16], r5 = arow[g + 20];
            const int r6 = arow[g + 24], r7 = arow[g + 28];
            const uint2 sv = *reinterpret_cast<const uint2*>(
                ftin + ((size_t)idv[p] << 6) + (h << 2));
            auto FL = [&](int r) -> uint2 {
                return *reinterpret_cast<const uint2*>(
                    ftin + ((size_t)r << 6) + (h << 2));
            };
            const uint2 f0 = FL(r0), f1 = FL(r1), f2 = FL(r2), f3 = FL(r3);
            const uint2 f4 = FL(r4), f5 = FL(r5), f6 = FL(r6), f7 = FL(r7);
            const uint2 s01 = pk_add_h2x2(f0, f1);
            const uint2 s23 = pk_add_h2x2(f2, f3);
            const uint2 s45 = pk_add_h2x2(f4, f5);
            const uint2 s67 = pk_add_h2x2(f6, f7);
            const uint2 q0 = pk_add_h2x2(s01, s23);
            const uint2 q1 = pk_add_h2x2(s45, s67);
            const uint2 tt = pk_add_h2x2(q0, q1);   // 8-way fp16 partial sums
            const half2_t tl = __builtin_bit_cast(half2_t, tt.x);
            const half2_t th = __builtin_bit_cast(half2_t, tt.y);
            float p0 = (float)tl.x, p1 = (float)tl.y;
            float p2 = (float)th.x, p3 = (float)th.y;
            p0 += __shfl_xor(p0, 16); p1 += __shfl_xor(p1, 16);
            p2 += __shfl_xor(p2, 16); p3 += __shfl_xor(p3, 16);
            p0 += __shfl_xor(p0, 32); p1 += __shfl_xor(p1, 32);
            p2 += __shfl_xor(p2, 32); p3 += __shfl_xor(p3, 32);
            const half2_t sl = __builtin_bit_cast(half2_t, sv.x);
            const half2_t sh = __builtin_bit_cast(half2_t, sv.y);
            const float s0 = (float)sl.x, s1 = (float)sl.y;
            const float s2 = (float)sh.x, s3 = (float)sh.y;
            const bool mul = (g & 1);               // g1/g3: "*" rows
            const float w0 = mul ? s0 * p0 : s0 + p0;
            const float w1 = mul ? s1 * p1 : s1 + p1;
            const float w2 = mul ? s2 * p2 : s2 + p2;
            const float w3 = mul ? s3 * p3 : s3 + p3;
            uint pk0, pk1;
            asm("v_cvt_pk_bf16_f32 %0, %1, %2" : "=v"(pk0) : "v"(w0), "v"(w1));
            asm("v_cvt_pk_bf16_f32 %0, %1, %2" : "=v"(pk1) : "v"(w2), "v"(w3));
            if (g < 2) {
                uint2 wq; wq.x = pk0; wq.y = pk1;
                *reinterpret_cast<uint2*>(
                    Aw + ((p << 8) + (wbyte ^ ((p & 7) << 4)))) = wq;
            }
        }
        // same-wave ds_write -> ds_read: lgkmcnt ordering, no barrier needed.
        // ---- MFMA: D[16 nodes][64] = A[16][128] x W[128][64] + b ----
        f32x4 acc0 = {bb0, bb0, bb0, bb0}, acc1 = {bb1, bb1, bb1, bb1};
        f32x4 acc2 = {bb2, bb2, bb2, bb2}, acc3 = {bb3, bb3, bb3, bb3};
#pragma unroll
        for (int c = 0; c < 4; ++c) {
            const int gran = ((c << 2) | lp) ^ mm7;
            const bf16x8 a = *reinterpret_cast<const bf16x8*>(
                Aw + (mrow << 8) + (gran << 4));
            acc0 = __builtin_amdgcn_mfma_f32_16x16x32_bf16(
                a, __builtin_bit_cast(bf16x8, Bg[(0 * 4 + c) * 64 + lane]), acc0, 0, 0, 0);
            acc1 = __builtin_amdgcn_mfma_f32_16x16x32_bf16(
                a, __builtin_bit_cast(bf16x8, Bg[(1 * 4 + c) * 64 + lane]), acc1, 0, 0, 0);
            acc2 = __builtin_amdgcn_mfma_f32_16x16x32_bf16(
                a, __builtin_bit_cast(bf16x8, Bg[(2 * 4 + c) * 64 + lane]), acc2, 0, 0, 0);
            acc3 = __builtin_amdgcn_mfma_f32_16x16x32_bf16(
                a, __builtin_bit_cast(bf16x8, Bg[(3 * 4 + c) * 64 + lane]), acc3, 0, 0, 0);
        }
        // ---- epilogue: relu (+ norm), store. C layout: col=lane&15,
        // node-in-tile = lp*4 + reg ----
        float z0[4], z1[4], z2[4], z3[4];
#pragma unroll
        for (int r = 0; r < 4; ++r) {
            z0[r] = fmaxf(acc0[r], 0.f);
            z1[r] = fmaxf(acc1[r], 0.f);
            z2[r] = fmaxf(acc2[r], 0.f);
            z3[r] = fmaxf(acc3[r], 0.f);
        }
        if (NORM) {
#pragma unroll
            for (int r = 0; r < 4; ++r) {
                float ss = z0[r] * z0[r] + z1[r] * z1[r] + z2[r] * z2[r] + z3[r] * z3[r];
                ss += __shfl_xor(ss, 1);
                ss += __shfl_xor(ss, 2);
                ss += __shfl_xor(ss, 4);
                ss += __shfl_xor(ss, 8);
                const float inv = 1.0f / fmaxf(sqrtf(ss), CEPS);
                z0[r] *= inv; z1[r] *= inv; z2[r] *= inv; z3[r] *= inv;
            }
        }
#pragma unroll
        for (int r = 0; r < 4; ++r) {
            const int node = base + (lp << 2) + r;
            if (node < nNodes) {
                OutT* orow = ftout + (size_t)node * CD + mrow;
                orow[0]  = (OutT)z0[r];
                orow[16] = (OutT)z1[r];
                orow[32] = (OutT)z2[r];
                orow[48] = (OutT)z3[r];
            }
        }
    }
}

extern "C" void kernel_launch(void* const* d_in, const int* in_sizes, int n_in,
                              void* d_out, int out_size, void* d_ws, size_t ws_size,
                              hipStream_t stream) {
    const float* node_feats  = (const float*)d_in[0];
    const int*   node_l1_ids = (const int*)d_in[1];
    const int*   adj1        = (const int*)d_in[2];
    const int*   node2_pos   = (const int*)d_in[3];
    const int*   adj2        = (const int*)d_in[4];
    const float* W1          = (const float*)d_in[5];
    const float* b1          = (const float*)d_in[6];
    const float* W2          = (const float*)d_in[7];
    const float* b2          = (const float*)d_in[8];
    float* out = (float*)d_out;

    __half* ft0 = (__half*)d_ws;                   // 25.6 MB
    __half* ft1 = ft0 + (size_t)CN0 * CD;          // 12.8 MB
    ushort* Wf1 = (ushort*)(ft1 + (size_t)CN1 * CD);  // 16 KB
    ushort* Wf2 = Wf1 + 8192;                          // 16 KB

    k_prepw<<<2, 256, 0, stream>>>(W1, W2, Wf1, Wf2);
    int t1 = CN0 * 8;
    k_lv0<<<(t1 + 255) / 256, 256, 0, stream>>>(node_feats, ft0);
    const int nB1 = (CN1 + 63) / 64;
    const int nB2 = (CN2 + 63) / 64;
    k_conv<false, __half><<<nB1, 256, 0, stream>>>(ft0, node_l1_ids, adj1, Wf1, b1, ft1, CN1);
    k_conv<true, float><<<nB2, 256, 0, stream>>>(ft1, node2_pos, adj2, Wf2, b2, out, CN2);
}